// Round 1
// baseline (2493.453 us; speedup 1.0000x reference)
//
#include <hip/hip_runtime.h>

// RoIAlign matching jax.image.scale_and_translate(method="linear", antialias=True)
// feature_map: [512][512][64] f32, boxes: [512][4] f32 (cx,cy,w,h), out: [512][32][32][64] f32

#define H_IN 512
#define W_IN 512
#define CH   64
#define NB   512
#define OW   32
#define WSTRIDE 33   // weights per (box,dim,o); odd stride -> conflict-free LDS
#define TAPS_MAX 33  // ks < 16 (w,h < 1) -> taps <= 2*ks+1 < 33

// ---------------------------------------------------------------------------
// Kernel 1: per (box, dim, o) tap table.
//   sample_f = (o+0.5)*inv - trans*inv - 0.5 ; ks = max(inv, 1)
//   weights  = max(0, 1 - |sample_f - i|/ks), normalized by sum over i in [0,512)
//   zero whole column if sum <= 1000*eps_f32 or sample_f outside [-0.5, 511.5]
// ---------------------------------------------------------------------------
__global__ __launch_bounds__(256) void roi_weights(const float* __restrict__ boxes,
                                                   float* __restrict__ wTab,
                                                   int* __restrict__ meta) {
    int tid = blockIdx.x * blockDim.x + threadIdx.x;
    if (tid >= NB * 2 * 32) return;
    int o   = tid & 31;
    int dim = (tid >> 5) & 1;   // 0 = y, 1 = x
    int b   = tid >> 6;

    float cx = boxes[b * 4 + 0];
    float cy = boxes[b * 4 + 1];
    float bw = boxes[b * 4 + 2];
    float bh = boxes[b * 4 + 3];
    float cc = dim ? cx : cy;
    float sz = dim ? bw : bh;
    float lo = cc - sz * 0.5f;        // x0 / y0 computed with PRE-clamp size (matches ref)
    sz = fmaxf(sz, 1e-6f);

    // mirror the reference's exact fp32 expression sequence
    float scale = (float)OW / (sz * (float)W_IN);
    float inv   = 1.0f / scale;
    float trans = (-lo * (float)OW) / sz;
    float s     = ((float)o + 0.5f) * inv - trans * inv - 0.5f;
    float ks    = fmaxf(inv, 1.0f);

    int i_lo = max((int)ceilf(s - ks), 0);
    int i_hi = min((int)floorf(s + ks), W_IN - 1);
    int cnt  = i_hi - i_lo + 1;
    if (cnt < 0) cnt = 0;
    if (cnt > TAPS_MAX) cnt = TAPS_MAX;  // memory-safety only; unreachable for valid boxes

    float sum = 0.0f;
    for (int k = 0; k < cnt; ++k) {
        float x = fabsf(s - (float)(i_lo + k)) / ks;
        sum += fmaxf(0.0f, 1.0f - x);
    }
    bool ok = (sum > 1.1920929e-4f) && (s >= -0.5f) && (s <= (float)W_IN - 0.5f);

    float* wout = wTab + ((size_t)(dim * NB + b) * 32 + o) * WSTRIDE;
    for (int k = 0; k < TAPS_MAX; ++k) {
        float w = 0.0f;
        if (ok && k < cnt) {
            float x = fabsf(s - (float)(i_lo + k)) / ks;
            w = fmaxf(0.0f, 1.0f - x) / sum;   // per-element divide, like jnp.divide
        }
        wout[k] = w;
    }
    int* m = meta + ((size_t)(dim * NB + b) * 32 + o) * 2;
    m[0] = i_lo;
    m[1] = ok ? cnt : 0;
}

// ---------------------------------------------------------------------------
// Kernel 2: one block per (box, oy). bid = oy*512 + box so all 32 oy-blocks of
// a box hit the same XCD under round-robin dispatch (L2 reuse of y-overlap).
// Thread t: ox = t>>3, channels [ (t&7)*8, +8 ).
// ---------------------------------------------------------------------------
__global__ __launch_bounds__(256) void roi_main(const float* __restrict__ fm,
                                                const float* __restrict__ wTab,
                                                const int* __restrict__ meta,
                                                float* __restrict__ out) {
    __shared__ float sWx[32 * WSTRIDE];
    __shared__ int   sMx[64];
    __shared__ float sWy[TAPS_MAX];
    __shared__ int   sMy[2];

    int bid = blockIdx.x;
    int box = bid & (NB - 1);
    int oy  = bid >> 9;
    int t   = threadIdx.x;

    const float* wxsrc = wTab + (size_t)(NB + box) * 32 * WSTRIDE;
    for (int i = t; i < 32 * WSTRIDE; i += 256) sWx[i] = wxsrc[i];
    const int* mxsrc = meta + (size_t)(NB + box) * 32 * 2;
    if (t < 64) sMx[t] = mxsrc[t];
    const float* wysrc = wTab + ((size_t)box * 32 + oy) * WSTRIDE;
    if (t < TAPS_MAX) sWy[t] = wysrc[t];
    if (t < 2) sMy[t] = meta[((size_t)box * 32 + oy) * 2 + t];
    __syncthreads();

    int ox = t >> 3;
    int c0 = (t & 7) * 8;
    int iy0 = sMy[0], cnty = sMy[1];
    int ix0 = sMx[ox * 2], cntx = sMx[ox * 2 + 1];
    const float* wxp = &sWx[ox * WSTRIDE];

    float acc0 = 0.f, acc1 = 0.f, acc2 = 0.f, acc3 = 0.f;
    float acc4 = 0.f, acc5 = 0.f, acc6 = 0.f, acc7 = 0.f;

    for (int ty = 0; ty < cnty; ++ty) {
        float wyv = sWy[ty];
        const float* rowp = fm + ((iy0 + ty) * W_IN + ix0) * CH + c0;
        for (int tx = 0; tx < cntx; ++tx) {
            float w = wyv * wxp[tx];
            float4 v0 = *(const float4*)(rowp);
            float4 v1 = *(const float4*)(rowp + 4);
            acc0 = fmaf(w, v0.x, acc0);
            acc1 = fmaf(w, v0.y, acc1);
            acc2 = fmaf(w, v0.z, acc2);
            acc3 = fmaf(w, v0.w, acc3);
            acc4 = fmaf(w, v1.x, acc4);
            acc5 = fmaf(w, v1.y, acc5);
            acc6 = fmaf(w, v1.z, acc6);
            acc7 = fmaf(w, v1.w, acc7);
            rowp += CH;
        }
    }

    float* op = out + ((size_t)(box * 32 + oy) * 32 + ox) * CH + c0;
    *(float4*)(op)     = make_float4(acc0, acc1, acc2, acc3);
    *(float4*)(op + 4) = make_float4(acc4, acc5, acc6, acc7);
}

extern "C" void kernel_launch(void* const* d_in, const int* in_sizes, int n_in,
                              void* d_out, int out_size, void* d_ws, size_t ws_size,
                              hipStream_t stream) {
    const float* fm    = (const float*)d_in[0];
    const float* boxes = (const float*)d_in[1];
    // d_in[2] = output_width (==32), hardcoded.

    float* wTab = (float*)d_ws;                                   // 2*512*32*33 f32 = 4.33 MB
    int*   meta = (int*)((char*)d_ws + (size_t)2 * NB * 32 * WSTRIDE * sizeof(float)); // 512 KB

    roi_weights<<<(NB * 2 * 32 + 255) / 256, 256, 0, stream>>>(boxes, wTab, meta);
    roi_main<<<NB * 32, 256, 0, stream>>>(fm, wTab, meta, (float*)d_out);
}

// Round 3
// 2170.332 us; speedup vs baseline: 1.1489x; 1.1489x over previous
//
#include <hip/hip_runtime.h>

// RoIAlign matching jax.image.scale_and_translate(method="linear", antialias=True)
// feature_map: [512][512][64] f32, boxes: [512][4] f32 (cx,cy,w,h), out: [512][32][32][64] f32

#define H_IN 512
#define W_IN 512
#define CH   64
#define NB   512
#define OW   32
#define WSTRIDE 33   // weights per (box,dim,o); odd stride -> conflict-free LDS
#define TAPS_MAX 33  // ks <= 16 -> taps <= 2*ks+1 = 33
#define UNION_MAX 64 // union of two adjacent oy windows <= 33+16=49; 64 for safety

// ---------------------------------------------------------------------------
// Kernel 1: per (box, dim, o) tap table (unchanged from R1 — verified correct).
// ---------------------------------------------------------------------------
__global__ __launch_bounds__(256) void roi_weights(const float* __restrict__ boxes,
                                                   float* __restrict__ wTab,
                                                   int* __restrict__ meta) {
    int tid = blockIdx.x * blockDim.x + threadIdx.x;
    if (tid >= NB * 2 * 32) return;
    int o   = tid & 31;
    int dim = (tid >> 5) & 1;   // 0 = y, 1 = x
    int b   = tid >> 6;

    float cx = boxes[b * 4 + 0];
    float cy = boxes[b * 4 + 1];
    float bw = boxes[b * 4 + 2];
    float bh = boxes[b * 4 + 3];
    float cc = dim ? cx : cy;
    float sz = dim ? bw : bh;
    float lo = cc - sz * 0.5f;        // x0/y0 use PRE-clamp size (matches ref)
    sz = fmaxf(sz, 1e-6f);

    float scale = (float)OW / (sz * (float)W_IN);
    float inv   = 1.0f / scale;
    float trans = (-lo * (float)OW) / sz;
    float s     = ((float)o + 0.5f) * inv - trans * inv - 0.5f;
    float ks    = fmaxf(inv, 1.0f);

    int i_lo = max((int)ceilf(s - ks), 0);
    int i_hi = min((int)floorf(s + ks), W_IN - 1);
    int cnt  = i_hi - i_lo + 1;
    if (cnt < 0) cnt = 0;
    if (cnt > TAPS_MAX) cnt = TAPS_MAX;

    float sum = 0.0f;
    for (int k = 0; k < cnt; ++k) {
        float x = fabsf(s - (float)(i_lo + k)) / ks;
        sum += fmaxf(0.0f, 1.0f - x);
    }
    bool ok = (sum > 1.1920929e-4f) && (s >= -0.5f) && (s <= (float)W_IN - 0.5f);

    float* wout = wTab + ((size_t)(dim * NB + b) * 32 + o) * WSTRIDE;
    for (int k = 0; k < TAPS_MAX; ++k) {
        float w = 0.0f;
        if (ok && k < cnt) {
            float x = fabsf(s - (float)(i_lo + k)) / ks;
            w = fmaxf(0.0f, 1.0f - x) / sum;
        }
        wout[k] = w;
    }
    int* m = meta + ((size_t)(dim * NB + b) * 32 + o) * 2;
    m[0] = i_lo;
    m[1] = ok ? cnt : 0;
}

// ---------------------------------------------------------------------------
// Kernel 2: one block per (box, oy-PAIR). bid = p*512 + box keeps all of a
// box's blocks on one XCD (512 % 8 == 0). Thread t: ox = t>>3, channels
// [(t&7)*8, +8). Each gather pass feeds BOTH oy accumulators (y-windows of
// adjacent oy overlap ~50% -> ~1.36x fewer gathers, 2x FMA per load).
// #pragma unroll 4 on the tap loop -> 8 loads in flight (was 2, latency-bound).
// ---------------------------------------------------------------------------
__global__ __launch_bounds__(256) void roi_main2(const float* __restrict__ fm,
                                                 const float* __restrict__ wTab,
                                                 const int* __restrict__ meta,
                                                 float* __restrict__ out) {
    __shared__ float sWx[32 * WSTRIDE];
    __shared__ int   sMx[64];
    __shared__ float sRow0[UNION_MAX];
    __shared__ float sRow1[UNION_MAX];
    __shared__ int   sMyA[2], sMyB[2];

    int bid = blockIdx.x;
    int box = bid & (NB - 1);
    int p   = bid >> 9;          // 0..15
    int oy0 = p * 2;
    int t   = threadIdx.x;

    const float* wxsrc = wTab + (size_t)(NB + box) * 32 * WSTRIDE;
    for (int i = t; i < 32 * WSTRIDE; i += 256) sWx[i] = wxsrc[i];
    const int* mxsrc = meta + (size_t)(NB + box) * 32 * 2;
    if (t < 64) sMx[t] = mxsrc[t];
    if (t >= 64 && t < 66) sMyA[t - 64] = meta[((size_t)box * 32 + oy0) * 2 + (t - 64)];
    if (t >= 66 && t < 68) sMyB[t - 66] = meta[((size_t)box * 32 + oy0 + 1) * 2 + (t - 66)];
    __syncthreads();

    int ia0 = sMyA[0], ca = sMyA[1];
    int ib0 = sMyB[0], cb = sMyB[1];
    int lo = 0x7fffffff, hi = -0x7fffffff;
    if (ca > 0) { lo = min(lo, ia0); hi = max(hi, ia0 + ca); }
    if (cb > 0) { lo = min(lo, ib0); hi = max(hi, ib0 + cb); }
    int u0 = (hi > lo) ? lo : 0;
    int cu = (hi > lo) ? (hi - lo) : 0;
    if (cu > UNION_MAX) cu = UNION_MAX;   // unreachable for valid boxes; memory safety

    const float* wyA = wTab + ((size_t)box * 32 + oy0) * WSTRIDE;
    const float* wyB = wyA + WSTRIDE;
    if (t < UNION_MAX) {
        int iy = u0 + t;
        int ra = iy - ia0, rb = iy - ib0;
        sRow0[t] = (t < cu && ra >= 0 && ra < ca) ? wyA[ra] : 0.0f;
        sRow1[t] = (t < cu && rb >= 0 && rb < cb) ? wyB[rb] : 0.0f;
    }
    __syncthreads();

    int ox = t >> 3;
    int c0 = (t & 7) * 8;
    int ix0 = sMx[ox * 2], cntx = sMx[ox * 2 + 1];
    const float* wxp = &sWx[ox * WSTRIDE];

    float a0 = 0.f, a1 = 0.f, a2 = 0.f, a3 = 0.f, a4 = 0.f, a5 = 0.f, a6 = 0.f, a7 = 0.f;
    float b0 = 0.f, b1 = 0.f, b2 = 0.f, b3 = 0.f, b4 = 0.f, b5 = 0.f, b6 = 0.f, b7 = 0.f;

    for (int r = 0; r < cu; ++r) {
        float wy0 = sRow0[r];
        float wy1 = sRow1[r];
        const float* rowp = fm + ((size_t)(u0 + r) * W_IN + ix0) * CH + c0;
        #pragma unroll 4
        for (int tx = 0; tx < cntx; ++tx) {
            float wxv = wxp[tx];
            float wa = wy0 * wxv;
            float wb = wy1 * wxv;
            float4 v0 = *(const float4*)(rowp);
            float4 v1 = *(const float4*)(rowp + 4);
            a0 = fmaf(wa, v0.x, a0);
            a1 = fmaf(wa, v0.y, a1);
            a2 = fmaf(wa, v0.z, a2);
            a3 = fmaf(wa, v0.w, a3);
            a4 = fmaf(wa, v1.x, a4);
            a5 = fmaf(wa, v1.y, a5);
            a6 = fmaf(wa, v1.z, a6);
            a7 = fmaf(wa, v1.w, a7);
            b0 = fmaf(wb, v0.x, b0);
            b1 = fmaf(wb, v0.y, b1);
            b2 = fmaf(wb, v0.z, b2);
            b3 = fmaf(wb, v0.w, b3);
            b4 = fmaf(wb, v1.x, b4);
            b5 = fmaf(wb, v1.y, b5);
            b6 = fmaf(wb, v1.z, b6);
            b7 = fmaf(wb, v1.w, b7);
            rowp += CH;
        }
    }

    float* opA = out + (((size_t)box * 32 + oy0) * 32 + ox) * CH + c0;
    float* opB = opA + 32 * CH;   // next oy row of this box
    *(float4*)(opA)     = make_float4(a0, a1, a2, a3);
    *(float4*)(opA + 4) = make_float4(a4, a5, a6, a7);
    *(float4*)(opB)     = make_float4(b0, b1, b2, b3);
    *(float4*)(opB + 4) = make_float4(b4, b5, b6, b7);
}

extern "C" void kernel_launch(void* const* d_in, const int* in_sizes, int n_in,
                              void* d_out, int out_size, void* d_ws, size_t ws_size,
                              hipStream_t stream) {
    const float* fm    = (const float*)d_in[0];
    const float* boxes = (const float*)d_in[1];
    // d_in[2] = output_width (==32), hardcoded.

    float* wTab = (float*)d_ws;                                   // 2*512*32*33 f32 = 4.33 MB
    int*   meta = (int*)((char*)d_ws + (size_t)2 * NB * 32 * WSTRIDE * sizeof(float)); // 512 KB

    roi_weights<<<(NB * 2 * 32 + 255) / 256, 256, 0, stream>>>(boxes, wTab, meta);
    roi_main2<<<NB * 16, 256, 0, stream>>>(fm, wTab, meta, (float*)d_out);
}